// Round 6
// baseline (292.370 us; speedup 1.0000x reference)
//
#include <hip/hip_runtime.h>

#define NN 8192
#define TT 60
#define DF 6
#define HH 64
#define GG 256   // 4*H
#define RS 132   // sorted-row stride: [0..63] u*last, [64..127] w*last, [128] u, [129] w
#define CH 128   // scan chunk rows
#define NCH (NN / CH)   // 64 chunks

typedef _Float16 half8 __attribute__((ext_vector_type(8)));
typedef float f32x4 __attribute__((ext_vector_type(4)));
#define MFMA16(a, b, c) __builtin_amdgcn_mfma_f32_16x16x32_f16((a), (b), (c), 0, 0, 0)

__device__ __forceinline__ float sigmoidf_(float x) {
    return __builtin_amdgcn_rcpf(1.0f + __expf(-x));
}
__device__ __forceinline__ float tanhf_(float x) {
    return __builtin_fmaf(2.0f, __builtin_amdgcn_rcpf(1.0f + __expf(-2.0f * x)), -1.0f);
}
__device__ __forceinline__ float lrelu_(float x) { return x > 0.0f ? x : 0.01f * x; }

__device__ __forceinline__ half8 ldw8(const float* __restrict__ p) {
    const float4* q = (const float4*)p;
    float4 u = q[0], v = q[1];
    half8 r;
    r[0]=(_Float16)u.x; r[1]=(_Float16)u.y; r[2]=(_Float16)u.z; r[3]=(_Float16)u.w;
    r[4]=(_Float16)v.x; r[5]=(_Float16)v.y; r[6]=(_Float16)v.z; r[7]=(_Float16)v.w;
    return r;
}

// ---------------------------------------------------------------------------
// MFMA 2-layer LSTM, software-pipelined across layers.
// Block = 16 rows, 8 waves (512 thr). Waves 0-3 (grp0) compute layer 0 of
// step i; waves 4-7 (grp1) compute layer 1 of step i-1 in the same iteration.
// One barrier per iteration (61 iters). Parity buffers: at iter i, h0buf[i&1]
// holds h0_{i-1}, h1buf[i&1] holds h1_{i-2}; writes go to buf[i&1 ^ 1].
// Weight frags unified in wA/wB so both grp paths share registers.
// ---------------------------------------------------------------------------
#define SXW (TT * 8 + 8)

__global__ __launch_bounds__(512, 4)
void lstm_fused_kernel(const float* __restrict__ x,
                       const float* __restrict__ Wih0, const float* __restrict__ Whh0,
                       const float* __restrict__ bih0, const float* __restrict__ bhh0,
                       const float* __restrict__ Wih1, const float* __restrict__ Whh1,
                       const float* __restrict__ bih1, const float* __restrict__ bhh1,
                       float* __restrict__ last_out)
{
    __shared__ _Float16 sxp[16][SXW];
    __shared__ _Float16 h0buf[2][16][72];
    __shared__ _Float16 h1buf[2][16][72];
    __shared__ _Float16 zero16[8];

    const int tid  = threadIdx.x;
    const int w    = tid >> 6;         // 0..7
    const int grp  = w >> 2;           // 0: layer0, 1: layer1
    const int cg   = w & 3;            // col-group
    const int lane = tid & 63;
    const int quad = lane >> 4;
    const int l15  = lane & 15;
    const int hc   = cg * 16 + l15;
    const int n0   = blockIdx.x * 16;

    for (int i = tid; i < 16 * SXW / 2; i += 512) ((unsigned*)sxp)[i] = 0u;
    for (int i = tid; i < 2 * 16 * 72 / 2; i += 512) ((unsigned*)h0buf)[i] = 0u;
    for (int i = tid; i < 2 * 16 * 72 / 2; i += 512) ((unsigned*)h1buf)[i] = 0u;
    if (tid < 4) ((unsigned*)zero16)[tid] = 0u;
    __syncthreads();

    for (int idx = tid; idx < 16 * TT * DF; idx += 512) {
        const int m = idx / (TT * DF);
        const int r = idx - m * (TT * DF);
        const int t = r / DF;
        const int d = r - t * DF;
        sxp[m][t * 8 + d] = (_Float16)x[(size_t)(n0 + m) * (TT * DF) + r];
    }

    // Unified weight registers (grp0: wA=Whh0, wB[nt][0]=x-proj; grp1: wA=Wih1, wB=Whh1)
    half8 wA[4][2], wB[4][2];
    float bias[4];
    half8 hzero;
    #pragma unroll
    for (int j = 0; j < 8; j++) hzero[j] = (_Float16)0.f;

    if (grp == 0) {
        #pragma unroll
        for (int nt = 0; nt < 4; nt++) {
            const int g = nt * 64 + hc;
            wA[nt][0] = ldw8(Whh0 + (size_t)g * HH + quad * 8);
            wA[nt][1] = ldw8(Whh0 + (size_t)g * HH + 32 + quad * 8);
            bias[nt]  = bih0[g] + bhh0[g];
            half8 t = hzero;
            if (quad == 0) {
                #pragma unroll
                for (int j = 0; j < DF; j++) t[j] = (_Float16)Wih0[g * DF + j];
            }
            wB[nt][0] = t;
            wB[nt][1] = hzero;
        }
    } else {
        #pragma unroll
        for (int nt = 0; nt < 4; nt++) {
            const int g = nt * 64 + hc;
            wA[nt][0] = ldw8(Wih1 + (size_t)g * HH + quad * 8);
            wA[nt][1] = ldw8(Wih1 + (size_t)g * HH + 32 + quad * 8);
            wB[nt][0] = ldw8(Whh1 + (size_t)g * HH + quad * 8);
            wB[nt][1] = ldw8(Whh1 + (size_t)g * HH + 32 + quad * 8);
            bias[nt]  = bih1[g] + bhh1[g];
        }
    }

    float cs[4] = {0.f, 0.f, 0.f, 0.f};
    __syncthreads();

    for (int i = 0; i <= TT; i++) {
        const int p = i & 1;
        if (grp == 0) {
            if (i < TT) {
                const half8 a0 = *(const half8*)&h0buf[p][l15][quad * 8];
                const half8 a1 = *(const half8*)&h0buf[p][l15][32 + quad * 8];
                const _Float16* xap = (quad == 0) ? &sxp[l15][i * 8] : zero16;
                const half8 ax = *(const half8*)xap;
                f32x4 gv[4];
                #pragma unroll
                for (int nt = 0; nt < 4; nt++) {
                    f32x4 c; c[0] = bias[nt]; c[1] = bias[nt]; c[2] = bias[nt]; c[3] = bias[nt];
                    c = MFMA16(ax, wB[nt][0], c);
                    c = MFMA16(a0, wA[nt][0], c);
                    c = MFMA16(a1, wA[nt][1], c);
                    gv[nt] = c;
                }
                _Float16 (*h0w)[72] = h0buf[p ^ 1];
                #pragma unroll
                for (int reg = 0; reg < 4; reg++) {
                    const float gi = gv[0][reg], gf = gv[1][reg], gc = gv[2][reg], go = gv[3][reg];
                    const float cc = sigmoidf_(gf) * cs[reg] + sigmoidf_(gi) * tanhf_(gc);
                    cs[reg] = cc;
                    h0w[quad * 4 + reg][hc] = (_Float16)(sigmoidf_(go) * tanhf_(cc));
                }
            }
        } else {
            if (i > 0) {
                const half8 a00 = *(const half8*)&h0buf[p][l15][quad * 8];
                const half8 a01 = *(const half8*)&h0buf[p][l15][32 + quad * 8];
                const half8 a10 = *(const half8*)&h1buf[p][l15][quad * 8];
                const half8 a11 = *(const half8*)&h1buf[p][l15][32 + quad * 8];
                f32x4 gv[4];
                #pragma unroll
                for (int nt = 0; nt < 4; nt++) {
                    f32x4 c; c[0] = bias[nt]; c[1] = bias[nt]; c[2] = bias[nt]; c[3] = bias[nt];
                    c = MFMA16(a00, wA[nt][0], c);
                    c = MFMA16(a01, wA[nt][1], c);
                    c = MFMA16(a10, wB[nt][0], c);
                    c = MFMA16(a11, wB[nt][1], c);
                    gv[nt] = c;
                }
                _Float16 (*h1w)[72] = h1buf[p ^ 1];
                #pragma unroll
                for (int reg = 0; reg < 4; reg++) {
                    const float gi = gv[0][reg], gf = gv[1][reg], gc = gv[2][reg], go = gv[3][reg];
                    const float cc = sigmoidf_(gf) * cs[reg] + sigmoidf_(gi) * tanhf_(gc);
                    cs[reg] = cc;
                    const float hv = sigmoidf_(go) * tanhf_(cc);
                    h1w[quad * 4 + reg][hc] = (_Float16)hv;
                    if (i == TT) last_out[(size_t)(n0 + quad * 4 + reg) * HH + hc] = hv;
                }
            }
        }
        __syncthreads();
    }
}

// ---------------------------------------------------------------------------
// GAT prep (unchanged): s1, s2, per-block max of s1.
// ---------------------------------------------------------------------------
__global__ void gat_prep_kernel(const float* __restrict__ last,
                                const float* __restrict__ Wt, const float* __restrict__ bt,
                                const float* __restrict__ a,
                                float* __restrict__ s1, float* __restrict__ s2,
                                float* __restrict__ blkmax)
{
    __shared__ float sWtT[HH][HH + 1];
    __shared__ float slast[16][HH];
    __shared__ float sbt[HH], sa1[HH], sa2[HH];
    __shared__ float swm[4];
    const int tid = threadIdx.x;
    for (int idx = tid; idx < HH * HH; idx += 256) {
        const int h = idx >> 6, d = idx & 63;
        sWtT[d][h] = Wt[idx];
    }
    if (tid < HH) { sbt[tid] = bt[tid]; sa1[tid] = a[tid]; sa2[tid] = a[HH + tid]; }
    const int n0 = blockIdx.x * 16;
    for (int idx = tid; idx < 16 * HH; idx += 256)
        (&slast[0][0])[idx] = last[(size_t)n0 * HH + idx];
    __syncthreads();
    const int w = tid >> 6, l = tid & 63;
    float wmax = -1e30f;
    for (int rr = 0; rr < 4; rr++) {
        const int r = w * 4 + rr;
        float acc = sbt[l];
        #pragma unroll
        for (int d = 0; d < HH; d++) acc += slast[r][d] * sWtT[d][l];
        float p1 = acc * sa1[l], p2 = acc * sa2[l];
        #pragma unroll
        for (int off = 32; off > 0; off >>= 1) {
            p1 += __shfl_xor(p1, off);
            p2 += __shfl_xor(p2, off);
        }
        if (l == 0) { s1[n0 + r] = p1; s2[n0 + r] = p2; }
        wmax = fmaxf(wmax, p1);
    }
    if (l == 0) swm[w] = wmax;
    __syncthreads();
    if (tid == 0) blkmax[blockIdx.x] = fmaxf(fmaxf(swm[0], swm[1]), fmaxf(swm[2], swm[3]));
}

// ---------------------------------------------------------------------------
// Finalize (grid=32, unchanged).
// ---------------------------------------------------------------------------
__global__ void gat_finalize_kernel(const float* __restrict__ s1, const float* __restrict__ s2,
                                    const float* __restrict__ blkmax,
                                    float* __restrict__ Z, float* __restrict__ Ai, float* __restrict__ Bi,
                                    float* __restrict__ Dj, float* __restrict__ Uj, float* __restrict__ Wj,
                                    int* __restrict__ rank)
{
    __shared__ float red[256];
    const int tid = threadIdx.x;
    red[tid] = fmaxf(blkmax[tid], blkmax[tid + 256]);
    __syncthreads();
    for (int s = 128; s > 0; s >>= 1) {
        if (tid < s) red[tid] = fmaxf(red[tid], red[tid + s]);
        __syncthreads();
    }
    const float s1max = red[0];
    for (int i = blockIdx.x * 256 + tid; i < NN; i += 256 * 32) {
        const float z  = s2[i] + s1max;
        const float mi = lrelu_(z);
        Z[i]  = z;
        Ai[i] = __expf(z - mi);
        Bi[i] = __expf(0.01f * z - mi);
        const float d = s1[i] - s1max;
        Dj[i] = d;
        Uj[i] = __expf(d);
        Wj[i] = __expf(0.01f * d);
        rank[i] = 0;
    }
}

// ---------------------------------------------------------------------------
// Rank (unchanged).
// ---------------------------------------------------------------------------
__global__ __launch_bounds__(256)
void rank_kernel(const float* __restrict__ Dj, int* __restrict__ rank)
{
    __shared__ float sd[1024];
    const int tid = threadIdx.x;
    const int j   = blockIdx.x * 256 + tid;
    const float dj = Dj[j];
    const int kbase = blockIdx.y * 1024;
    for (int i = tid; i < 1024; i += 256) sd[i] = Dj[kbase + i];
    __syncthreads();
    int cnt = 0;
    #pragma unroll 4
    for (int q = 0; q < 256; q++) {
        const float4 dk = ((const float4*)sd)[q];
        const int k0 = kbase + q * 4;
        cnt += (dk.x < dj || (dk.x == dj && k0     < j)) ? 1 : 0;
        cnt += (dk.y < dj || (dk.y == dj && k0 + 1 < j)) ? 1 : 0;
        cnt += (dk.z < dj || (dk.z == dj && k0 + 2 < j)) ? 1 : 0;
        cnt += (dk.w < dj || (dk.w == dj && k0 + 3 < j)) ? 1 : 0;
    }
    atomicAdd(&rank[j], cnt);
}

// ---------------------------------------------------------------------------
// Scatter (unchanged).
// ---------------------------------------------------------------------------
__global__ __launch_bounds__(256)
void scatter_kernel(const float* __restrict__ last,
                    const float* __restrict__ Dj, const float* __restrict__ Uj,
                    const float* __restrict__ Wj, const int* __restrict__ rank,
                    float* __restrict__ sortedRow, float* __restrict__ sortedD)
{
    const int tid = threadIdx.x;
    const int wv = tid >> 6, lane = tid & 63;
    #pragma unroll
    for (int it = 0; it < 8; it++) {
        const int j = blockIdx.x * 32 + wv * 8 + it;
        const int r = rank[j];
        const float u = Uj[j], w = Wj[j];
        const float lv = last[(size_t)j * HH + lane];
        float* row = sortedRow + (size_t)r * RS;
        row[lane]      = u * lv;
        row[64 + lane] = w * lv;
        if (lane == 0) {
            row[128] = u;
            row[129] = w;
            sortedD[r] = Dj[j];
        }
    }
}

// ---------------------------------------------------------------------------
// scanA: per-chunk column sums (64 blocks, coalesced).
// ---------------------------------------------------------------------------
__global__ __launch_bounds__(256)
void scanA_kernel(const float* __restrict__ sortedRow, float* __restrict__ chunkSum)
{
    const int c = threadIdx.x;
    if (c >= 130) return;
    const int b = blockIdx.x;
    const float* base = sortedRow + (size_t)b * CH * RS + c;
    float s = 0.f;
    #pragma unroll 8
    for (int r = 0; r < CH; r++) s += base[(size_t)r * RS];
    chunkSum[b * RS + c] = s;
}

// ---------------------------------------------------------------------------
// scanC: fill PP; chunk offset computed in-block from chunkSum (scanB folded
// in: 64 independent coalesced loads + masked add per thread — no serial
// single-block dependency chain).
// ---------------------------------------------------------------------------
__global__ __launch_bounds__(256)
void scanC_kernel(const float* __restrict__ sortedRow, const float* __restrict__ chunkSum,
                  float* __restrict__ PP)
{
    const int c = threadIdx.x;
    if (c >= 130) return;
    const int b = blockIdx.x;
    const bool rev = (c < 64) || (c == 128);
    float run = 0.f;
    #pragma unroll 8
    for (int bb = 0; bb < NCH; bb++) {
        const float v = chunkSum[bb * RS + c];
        const bool take = rev ? (bb > b) : (bb < b);
        run += take ? v : 0.f;
    }
    if (rev) {
        if (b == NCH - 1) PP[(size_t)NN * RS + c] = 0.f;
        #pragma unroll 4
        for (int r = CH - 1; r >= 0; r--) {
            const size_t t = (size_t)b * CH + r;
            run += sortedRow[t * RS + c];
            PP[t * RS + c] = run;
        }
    } else {
        #pragma unroll 4
        for (int r = 0; r < CH; r++) {
            const size_t t = (size_t)b * CH + r;
            PP[t * RS + c] = run;
            run += sortedRow[t * RS + c];
        }
        if (b == NCH - 1) PP[(size_t)NN * RS + c] = run;
    }
}

// ---------------------------------------------------------------------------
// Fused apply + FC head: per i, binary-search threshold, combine branch sums,
// residual, then immediately hidden = lrelu(g @ Wfc^T + bfc), out = hidden·Wout
// + bout — gout never touches global memory.
// ---------------------------------------------------------------------------
__global__ __launch_bounds__(256)
void applyfc_kernel(const float* __restrict__ last,
                    const float* __restrict__ Z, const float* __restrict__ Ai, const float* __restrict__ Bi,
                    const float* __restrict__ sortedD, const float* __restrict__ PP,
                    const float* __restrict__ Wfc, const float* __restrict__ bfc,
                    const float* __restrict__ Wout, const float* __restrict__ bout,
                    float* __restrict__ out)
{
    __shared__ float sW[HH][HH + 1];
    __shared__ float sb[HH], sa[HH];
    const int tid = threadIdx.x;
    for (int idx = tid; idx < HH * HH; idx += 256) {
        const int h = idx >> 6, d = idx & 63;
        sW[d][h] = Wfc[idx];
    }
    if (tid < HH) { sb[tid] = bfc[tid]; sa[tid] = Wout[tid]; }
    __syncthreads();

    const int wv = tid >> 6, lane = tid & 63;
    const int base_i = (blockIdx.x * 4 + wv) * 8;
    const float bo = bout[0];
    for (int batch = 0; batch < 2; batch++) {
        const int i0 = base_i + batch * 4;
        float zi[4]; int lo[4], hi[4];
        #pragma unroll
        for (int q = 0; q < 4; q++) { zi[q] = Z[i0 + q]; lo[q] = 0; hi[q] = NN; }
        for (int iter = 0; iter < 13; iter++) {
            #pragma unroll
            for (int q = 0; q < 4; q++) {
                if (lo[q] < hi[q]) {
                    const int mid = (lo[q] + hi[q]) >> 1;
                    const float dm = sortedD[mid];
                    if (zi[q] + dm > 0.f) hi[q] = mid; else lo[q] = mid + 1;
                }
            }
        }
        #pragma unroll
        for (int q = 0; q < 4; q++) {
            const int i = i0 + q;
            const int t = lo[q];
            const float ai = Ai[i], bi = Bi[i];
            const float* row = PP + (size_t)t * RS;
            const float pu  = row[lane];
            const float pw  = row[64 + lane];
            const float pud = row[128];
            const float pwd = row[129];
            const float numer = bi * pw + ai * pu;
            const float den   = bi * pwd + ai * pud;
            const float lv = last[(size_t)i * HH + lane];
            const float gv = numer * __builtin_amdgcn_rcpf(den) + lv;   // gout[i][lane]
            // FC head, row-local:
            float acc = sb[lane];
            #pragma unroll
            for (int d = 0; d < HH; d++) acc += __shfl(gv, d) * sW[d][lane];
            float prod = lrelu_(acc) * sa[lane];
            #pragma unroll
            for (int off = 32; off > 0; off >>= 1) prod += __shfl_xor(prod, off);
            if (lane == 0) out[i] = prod + bo;
        }
    }
}

extern "C" void kernel_launch(void* const* d_in, const int* in_sizes, int n_in,
                              void* d_out, int out_size, void* d_ws, size_t ws_size,
                              hipStream_t stream)
{
    (void)in_sizes; (void)n_in; (void)out_size; (void)ws_size;
    const float* x    = (const float*)d_in[0];
    const float* Wih0 = (const float*)d_in[1];
    const float* Whh0 = (const float*)d_in[2];
    const float* bih0 = (const float*)d_in[3];
    const float* bhh0 = (const float*)d_in[4];
    const float* Wih1 = (const float*)d_in[5];
    const float* Whh1 = (const float*)d_in[6];
    const float* bih1 = (const float*)d_in[7];
    const float* bhh1 = (const float*)d_in[8];
    const float* Wt   = (const float*)d_in[9];
    const float* bt   = (const float*)d_in[10];
    const float* a    = (const float*)d_in[11];
    const float* Wfc  = (const float*)d_in[12];
    const float* bfc  = (const float*)d_in[13];
    const float* Wout = (const float*)d_in[14];
    const float* bout = (const float*)d_in[15];
    float* out = (float*)d_out;

    float* ws        = (float*)d_ws;
    float* last      = ws;                        // N*H
    float* s1        = last + (size_t)NN*HH;      // N
    float* s2        = s1 + NN;
    float* Z         = s2 + NN;
    float* Ai        = Z + NN;
    float* Bi        = Ai + NN;
    float* Dj        = Bi + NN;
    float* Uj        = Dj + NN;
    float* Wj        = Uj + NN;
    float* blkmax    = Wj + NN;                   // 512
    int*   rank      = (int*)(blkmax + 512);      // N ints
    float* sortedD   = (float*)(rank + NN);       // N
    float* sortedRow = sortedD + NN;              // N*RS
    float* PP        = sortedRow + (size_t)NN*RS; // (N+1)*RS
    float* chunkSum  = PP + (size_t)(NN+1)*RS;    // NCH*RS

    lstm_fused_kernel<<<dim3(NN / 16), dim3(512), 0, stream>>>(
        x, Wih0, Whh0, bih0, bhh0, Wih1, Whh1, bih1, bhh1, last);
    gat_prep_kernel<<<dim3(NN / 16), dim3(256), 0, stream>>>(
        last, Wt, bt, a, s1, s2, blkmax);
    gat_finalize_kernel<<<dim3(32), dim3(256), 0, stream>>>(
        s1, s2, blkmax, Z, Ai, Bi, Dj, Uj, Wj, rank);
    rank_kernel<<<dim3(NN / 256, 8), dim3(256), 0, stream>>>(Dj, rank);
    scatter_kernel<<<dim3(NN / 32), dim3(256), 0, stream>>>(
        last, Dj, Uj, Wj, rank, sortedRow, sortedD);
    scanA_kernel<<<dim3(NCH), dim3(256), 0, stream>>>(sortedRow, chunkSum);
    scanC_kernel<<<dim3(NCH), dim3(256), 0, stream>>>(sortedRow, chunkSum, PP);
    applyfc_kernel<<<dim3(NN / 32), dim3(256), 0, stream>>>(
        last, Z, Ai, Bi, sortedD, PP, Wfc, bfc, Wout, bout, out);
}

// Round 7
// 287.150 us; speedup vs baseline: 1.0182x; 1.0182x over previous
//
#include <hip/hip_runtime.h>

#define NN 8192
#define TT 60
#define DF 6
#define HH 64
#define GG 256   // 4*H
#define RS 132   // sorted-row stride: [0..63] u*last, [64..127] w*last, [128] u, [129] w
#define CH 32    // scan chunk rows (small => wide grids, short serial walks)
#define NCH (NN / CH)   // 256 chunks

typedef _Float16 half8 __attribute__((ext_vector_type(8)));
typedef float f32x4 __attribute__((ext_vector_type(4)));
#define MFMA16(a, b, c) __builtin_amdgcn_mfma_f32_16x16x32_f16((a), (b), (c), 0, 0, 0)

__device__ __forceinline__ float sigmoidf_(float x) {
    return __builtin_amdgcn_rcpf(1.0f + __expf(-x));
}
__device__ __forceinline__ float tanhf_(float x) {
    return __builtin_fmaf(2.0f, __builtin_amdgcn_rcpf(1.0f + __expf(-2.0f * x)), -1.0f);
}
__device__ __forceinline__ float lrelu_(float x) { return x > 0.0f ? x : 0.01f * x; }

__device__ __forceinline__ half8 ldw8(const float* __restrict__ p) {
    const float4* q = (const float4*)p;
    float4 u = q[0], v = q[1];
    half8 r;
    r[0]=(_Float16)u.x; r[1]=(_Float16)u.y; r[2]=(_Float16)u.z; r[3]=(_Float16)u.w;
    r[4]=(_Float16)v.x; r[5]=(_Float16)v.y; r[6]=(_Float16)v.z; r[7]=(_Float16)v.w;
    return r;
}

// ---------------------------------------------------------------------------
// MFMA 2-layer LSTM, software-pipelined across layers (unchanged from R6).
// ---------------------------------------------------------------------------
#define SXW (TT * 8 + 8)

__global__ __launch_bounds__(512, 4)
void lstm_fused_kernel(const float* __restrict__ x,
                       const float* __restrict__ Wih0, const float* __restrict__ Whh0,
                       const float* __restrict__ bih0, const float* __restrict__ bhh0,
                       const float* __restrict__ Wih1, const float* __restrict__ Whh1,
                       const float* __restrict__ bih1, const float* __restrict__ bhh1,
                       float* __restrict__ last_out)
{
    __shared__ _Float16 sxp[16][SXW];
    __shared__ _Float16 h0buf[2][16][72];
    __shared__ _Float16 h1buf[2][16][72];
    __shared__ _Float16 zero16[8];

    const int tid  = threadIdx.x;
    const int w    = tid >> 6;
    const int grp  = w >> 2;
    const int cg   = w & 3;
    const int lane = tid & 63;
    const int quad = lane >> 4;
    const int l15  = lane & 15;
    const int hc   = cg * 16 + l15;
    const int n0   = blockIdx.x * 16;

    for (int i = tid; i < 16 * SXW / 2; i += 512) ((unsigned*)sxp)[i] = 0u;
    for (int i = tid; i < 2 * 16 * 72 / 2; i += 512) ((unsigned*)h0buf)[i] = 0u;
    for (int i = tid; i < 2 * 16 * 72 / 2; i += 512) ((unsigned*)h1buf)[i] = 0u;
    if (tid < 4) ((unsigned*)zero16)[tid] = 0u;
    __syncthreads();

    for (int idx = tid; idx < 16 * TT * DF; idx += 512) {
        const int m = idx / (TT * DF);
        const int r = idx - m * (TT * DF);
        const int t = r / DF;
        const int d = r - t * DF;
        sxp[m][t * 8 + d] = (_Float16)x[(size_t)(n0 + m) * (TT * DF) + r];
    }

    half8 wA[4][2], wB[4][2];
    float bias[4];
    half8 hzero;
    #pragma unroll
    for (int j = 0; j < 8; j++) hzero[j] = (_Float16)0.f;

    if (grp == 0) {
        #pragma unroll
        for (int nt = 0; nt < 4; nt++) {
            const int g = nt * 64 + hc;
            wA[nt][0] = ldw8(Whh0 + (size_t)g * HH + quad * 8);
            wA[nt][1] = ldw8(Whh0 + (size_t)g * HH + 32 + quad * 8);
            bias[nt]  = bih0[g] + bhh0[g];
            half8 t = hzero;
            if (quad == 0) {
                #pragma unroll
                for (int j = 0; j < DF; j++) t[j] = (_Float16)Wih0[g * DF + j];
            }
            wB[nt][0] = t;
            wB[nt][1] = hzero;
        }
    } else {
        #pragma unroll
        for (int nt = 0; nt < 4; nt++) {
            const int g = nt * 64 + hc;
            wA[nt][0] = ldw8(Wih1 + (size_t)g * HH + quad * 8);
            wA[nt][1] = ldw8(Wih1 + (size_t)g * HH + 32 + quad * 8);
            wB[nt][0] = ldw8(Whh1 + (size_t)g * HH + quad * 8);
            wB[nt][1] = ldw8(Whh1 + (size_t)g * HH + 32 + quad * 8);
            bias[nt]  = bih1[g] + bhh1[g];
        }
    }

    float cs[4] = {0.f, 0.f, 0.f, 0.f};
    __syncthreads();

    for (int i = 0; i <= TT; i++) {
        const int p = i & 1;
        if (grp == 0) {
            if (i < TT) {
                const half8 a0 = *(const half8*)&h0buf[p][l15][quad * 8];
                const half8 a1 = *(const half8*)&h0buf[p][l15][32 + quad * 8];
                const _Float16* xap = (quad == 0) ? &sxp[l15][i * 8] : zero16;
                const half8 ax = *(const half8*)xap;
                f32x4 gv[4];
                #pragma unroll
                for (int nt = 0; nt < 4; nt++) {
                    f32x4 c; c[0] = bias[nt]; c[1] = bias[nt]; c[2] = bias[nt]; c[3] = bias[nt];
                    c = MFMA16(ax, wB[nt][0], c);
                    c = MFMA16(a0, wA[nt][0], c);
                    c = MFMA16(a1, wA[nt][1], c);
                    gv[nt] = c;
                }
                _Float16 (*h0w)[72] = h0buf[p ^ 1];
                #pragma unroll
                for (int reg = 0; reg < 4; reg++) {
                    const float gi = gv[0][reg], gf = gv[1][reg], gc = gv[2][reg], go = gv[3][reg];
                    const float cc = sigmoidf_(gf) * cs[reg] + sigmoidf_(gi) * tanhf_(gc);
                    cs[reg] = cc;
                    h0w[quad * 4 + reg][hc] = (_Float16)(sigmoidf_(go) * tanhf_(cc));
                }
            }
        } else {
            if (i > 0) {
                const half8 a00 = *(const half8*)&h0buf[p][l15][quad * 8];
                const half8 a01 = *(const half8*)&h0buf[p][l15][32 + quad * 8];
                const half8 a10 = *(const half8*)&h1buf[p][l15][quad * 8];
                const half8 a11 = *(const half8*)&h1buf[p][l15][32 + quad * 8];
                f32x4 gv[4];
                #pragma unroll
                for (int nt = 0; nt < 4; nt++) {
                    f32x4 c; c[0] = bias[nt]; c[1] = bias[nt]; c[2] = bias[nt]; c[3] = bias[nt];
                    c = MFMA16(a00, wA[nt][0], c);
                    c = MFMA16(a01, wA[nt][1], c);
                    c = MFMA16(a10, wB[nt][0], c);
                    c = MFMA16(a11, wB[nt][1], c);
                    gv[nt] = c;
                }
                _Float16 (*h1w)[72] = h1buf[p ^ 1];
                #pragma unroll
                for (int reg = 0; reg < 4; reg++) {
                    const float gi = gv[0][reg], gf = gv[1][reg], gc = gv[2][reg], go = gv[3][reg];
                    const float cc = sigmoidf_(gf) * cs[reg] + sigmoidf_(gi) * tanhf_(gc);
                    cs[reg] = cc;
                    const float hv = sigmoidf_(go) * tanhf_(cc);
                    h1w[quad * 4 + reg][hc] = (_Float16)hv;
                    if (i == TT) last_out[(size_t)(n0 + quad * 4 + reg) * HH + hc] = hv;
                }
            }
        }
        __syncthreads();
    }
}

// ---------------------------------------------------------------------------
// GAT prep (unchanged).
// ---------------------------------------------------------------------------
__global__ void gat_prep_kernel(const float* __restrict__ last,
                                const float* __restrict__ Wt, const float* __restrict__ bt,
                                const float* __restrict__ a,
                                float* __restrict__ s1, float* __restrict__ s2,
                                float* __restrict__ blkmax)
{
    __shared__ float sWtT[HH][HH + 1];
    __shared__ float slast[16][HH];
    __shared__ float sbt[HH], sa1[HH], sa2[HH];
    __shared__ float swm[4];
    const int tid = threadIdx.x;
    for (int idx = tid; idx < HH * HH; idx += 256) {
        const int h = idx >> 6, d = idx & 63;
        sWtT[d][h] = Wt[idx];
    }
    if (tid < HH) { sbt[tid] = bt[tid]; sa1[tid] = a[tid]; sa2[tid] = a[HH + tid]; }
    const int n0 = blockIdx.x * 16;
    for (int idx = tid; idx < 16 * HH; idx += 256)
        (&slast[0][0])[idx] = last[(size_t)n0 * HH + idx];
    __syncthreads();
    const int w = tid >> 6, l = tid & 63;
    float wmax = -1e30f;
    for (int rr = 0; rr < 4; rr++) {
        const int r = w * 4 + rr;
        float acc = sbt[l];
        #pragma unroll
        for (int d = 0; d < HH; d++) acc += slast[r][d] * sWtT[d][l];
        float p1 = acc * sa1[l], p2 = acc * sa2[l];
        #pragma unroll
        for (int off = 32; off > 0; off >>= 1) {
            p1 += __shfl_xor(p1, off);
            p2 += __shfl_xor(p2, off);
        }
        if (l == 0) { s1[n0 + r] = p1; s2[n0 + r] = p2; }
        wmax = fmaxf(wmax, p1);
    }
    if (l == 0) swm[w] = wmax;
    __syncthreads();
    if (tid == 0) blkmax[blockIdx.x] = fmaxf(fmaxf(swm[0], swm[1]), fmaxf(swm[2], swm[3]));
}

// ---------------------------------------------------------------------------
// Finalize (grid=32, unchanged).
// ---------------------------------------------------------------------------
__global__ void gat_finalize_kernel(const float* __restrict__ s1, const float* __restrict__ s2,
                                    const float* __restrict__ blkmax,
                                    float* __restrict__ Z, float* __restrict__ Ai, float* __restrict__ Bi,
                                    float* __restrict__ Dj, float* __restrict__ Uj, float* __restrict__ Wj,
                                    int* __restrict__ rank)
{
    __shared__ float red[256];
    const int tid = threadIdx.x;
    red[tid] = fmaxf(blkmax[tid], blkmax[tid + 256]);
    __syncthreads();
    for (int s = 128; s > 0; s >>= 1) {
        if (tid < s) red[tid] = fmaxf(red[tid], red[tid + s]);
        __syncthreads();
    }
    const float s1max = red[0];
    for (int i = blockIdx.x * 256 + tid; i < NN; i += 256 * 32) {
        const float z  = s2[i] + s1max;
        const float mi = lrelu_(z);
        Z[i]  = z;
        Ai[i] = __expf(z - mi);
        Bi[i] = __expf(0.01f * z - mi);
        const float d = s1[i] - s1max;
        Dj[i] = d;
        Uj[i] = __expf(d);
        Wj[i] = __expf(0.01f * d);
        rank[i] = 0;
    }
}

// ---------------------------------------------------------------------------
// Rank (unchanged).
// ---------------------------------------------------------------------------
__global__ __launch_bounds__(256)
void rank_kernel(const float* __restrict__ Dj, int* __restrict__ rank)
{
    __shared__ float sd[1024];
    const int tid = threadIdx.x;
    const int j   = blockIdx.x * 256 + tid;
    const float dj = Dj[j];
    const int kbase = blockIdx.y * 1024;
    for (int i = tid; i < 1024; i += 256) sd[i] = Dj[kbase + i];
    __syncthreads();
    int cnt = 0;
    #pragma unroll 4
    for (int q = 0; q < 256; q++) {
        const float4 dk = ((const float4*)sd)[q];
        const int k0 = kbase + q * 4;
        cnt += (dk.x < dj || (dk.x == dj && k0     < j)) ? 1 : 0;
        cnt += (dk.y < dj || (dk.y == dj && k0 + 1 < j)) ? 1 : 0;
        cnt += (dk.z < dj || (dk.z == dj && k0 + 2 < j)) ? 1 : 0;
        cnt += (dk.w < dj || (dk.w == dj && k0 + 3 < j)) ? 1 : 0;
    }
    atomicAdd(&rank[j], cnt);
}

// ---------------------------------------------------------------------------
// Scatter (unchanged).
// ---------------------------------------------------------------------------
__global__ __launch_bounds__(256)
void scatter_kernel(const float* __restrict__ last,
                    const float* __restrict__ Dj, const float* __restrict__ Uj,
                    const float* __restrict__ Wj, const int* __restrict__ rank,
                    float* __restrict__ sortedRow, float* __restrict__ sortedD)
{
    const int tid = threadIdx.x;
    const int wv = tid >> 6, lane = tid & 63;
    #pragma unroll
    for (int it = 0; it < 8; it++) {
        const int j = blockIdx.x * 32 + wv * 8 + it;
        const int r = rank[j];
        const float u = Uj[j], w = Wj[j];
        const float lv = last[(size_t)j * HH + lane];
        float* row = sortedRow + (size_t)r * RS;
        row[lane]      = u * lv;
        row[64 + lane] = w * lv;
        if (lane == 0) {
            row[128] = u;
            row[129] = w;
            sortedD[r] = Dj[j];
        }
    }
}

// ---------------------------------------------------------------------------
// scanA: per-chunk column sums. NCH=256 blocks (full GPU), 32 rows each.
// ---------------------------------------------------------------------------
__global__ __launch_bounds__(256)
void scanA_kernel(const float* __restrict__ sortedRow, float* __restrict__ chunkSum)
{
    const int c = threadIdx.x;
    if (c >= 130) return;
    const int b = blockIdx.x;
    const float* base = sortedRow + (size_t)b * CH * RS + c;
    float s = 0.f;
    #pragma unroll 8
    for (int r = 0; r < CH; r++) s += base[(size_t)r * RS];
    chunkSum[b * RS + c] = s;
}

// ---------------------------------------------------------------------------
// scanC: fill PP. 256 blocks; in-block chunk offset from 256 independent
// coalesced chunkSum loads + masked add; then a 32-row serial walk.
// ---------------------------------------------------------------------------
__global__ __launch_bounds__(256)
void scanC_kernel(const float* __restrict__ sortedRow, const float* __restrict__ chunkSum,
                  float* __restrict__ PP)
{
    const int c = threadIdx.x;
    if (c >= 130) return;
    const int b = blockIdx.x;
    const bool rev = (c < 64) || (c == 128);
    float run = 0.f;
    #pragma unroll 8
    for (int bb = 0; bb < NCH; bb++) {
        const float v = chunkSum[bb * RS + c];
        const bool take = rev ? (bb > b) : (bb < b);
        run += take ? v : 0.f;
    }
    if (rev) {
        if (b == NCH - 1) PP[(size_t)NN * RS + c] = 0.f;
        #pragma unroll 4
        for (int r = CH - 1; r >= 0; r--) {
            const size_t t = (size_t)b * CH + r;
            run += sortedRow[t * RS + c];
            PP[t * RS + c] = run;
        }
    } else {
        #pragma unroll 4
        for (int r = 0; r < CH; r++) {
            const size_t t = (size_t)b * CH + r;
            PP[t * RS + c] = run;
            run += sortedRow[t * RS + c];
        }
        if (b == NCH - 1) PP[(size_t)NN * RS + c] = run;
    }
}

// ---------------------------------------------------------------------------
// Fused apply + FC head. sortedD staged in LDS: the 13-step binary-search
// dependent chain hits LDS broadcast (~40 cyc) instead of global (~200-900).
// ---------------------------------------------------------------------------
__global__ __launch_bounds__(256)
void applyfc_kernel(const float* __restrict__ last,
                    const float* __restrict__ Z, const float* __restrict__ Ai, const float* __restrict__ Bi,
                    const float* __restrict__ sortedD, const float* __restrict__ PP,
                    const float* __restrict__ Wfc, const float* __restrict__ bfc,
                    const float* __restrict__ Wout, const float* __restrict__ bout,
                    float* __restrict__ out)
{
    __shared__ float sdD[NN];          // 32 KB
    __shared__ float sW[HH][HH + 1];   // 16.25 KB
    __shared__ float sb[HH], sa[HH];
    const int tid = threadIdx.x;
    for (int idx = tid; idx < NN; idx += 256) sdD[idx] = sortedD[idx];
    for (int idx = tid; idx < HH * HH; idx += 256) {
        const int h = idx >> 6, d = idx & 63;
        sW[d][h] = Wfc[idx];
    }
    if (tid < HH) { sb[tid] = bfc[tid]; sa[tid] = Wout[tid]; }
    __syncthreads();

    const int wv = tid >> 6, lane = tid & 63;
    const int base_i = (blockIdx.x * 4 + wv) * 8;
    const float bo = bout[0];
    for (int batch = 0; batch < 2; batch++) {
        const int i0 = base_i + batch * 4;
        float zi[4]; int lo[4], hi[4];
        #pragma unroll
        for (int q = 0; q < 4; q++) { zi[q] = Z[i0 + q]; lo[q] = 0; hi[q] = NN; }
        for (int iter = 0; iter < 13; iter++) {
            #pragma unroll
            for (int q = 0; q < 4; q++) {
                if (lo[q] < hi[q]) {
                    const int mid = (lo[q] + hi[q]) >> 1;
                    const float dm = sdD[mid];
                    if (zi[q] + dm > 0.f) hi[q] = mid; else lo[q] = mid + 1;
                }
            }
        }
        #pragma unroll
        for (int q = 0; q < 4; q++) {
            const int i = i0 + q;
            const int t = lo[q];
            const float ai = Ai[i], bi = Bi[i];
            const float* row = PP + (size_t)t * RS;
            const float pu  = row[lane];
            const float pw  = row[64 + lane];
            const float pud = row[128];
            const float pwd = row[129];
            const float numer = bi * pw + ai * pu;
            const float den   = bi * pwd + ai * pud;
            const float lv = last[(size_t)i * HH + lane];
            const float gv = numer * __builtin_amdgcn_rcpf(den) + lv;
            float acc = sb[lane];
            #pragma unroll
            for (int d = 0; d < HH; d++) acc += __shfl(gv, d) * sW[d][lane];
            float prod = lrelu_(acc) * sa[lane];
            #pragma unroll
            for (int off = 32; off > 0; off >>= 1) prod += __shfl_xor(prod, off);
            if (lane == 0) out[i] = prod + bo;
        }
    }
}

extern "C" void kernel_launch(void* const* d_in, const int* in_sizes, int n_in,
                              void* d_out, int out_size, void* d_ws, size_t ws_size,
                              hipStream_t stream)
{
    (void)in_sizes; (void)n_in; (void)out_size; (void)ws_size;
    const float* x    = (const float*)d_in[0];
    const float* Wih0 = (const float*)d_in[1];
    const float* Whh0 = (const float*)d_in[2];
    const float* bih0 = (const float*)d_in[3];
    const float* bhh0 = (const float*)d_in[4];
    const float* Wih1 = (const float*)d_in[5];
    const float* Whh1 = (const float*)d_in[6];
    const float* bih1 = (const float*)d_in[7];
    const float* bhh1 = (const float*)d_in[8];
    const float* Wt   = (const float*)d_in[9];
    const float* bt   = (const float*)d_in[10];
    const float* a    = (const float*)d_in[11];
    const float* Wfc  = (const float*)d_in[12];
    const float* bfc  = (const float*)d_in[13];
    const float* Wout = (const float*)d_in[14];
    const float* bout = (const float*)d_in[15];
    float* out = (float*)d_out;

    float* ws        = (float*)d_ws;
    float* last      = ws;                        // N*H
    float* s1        = last + (size_t)NN*HH;      // N
    float* s2        = s1 + NN;
    float* Z         = s2 + NN;
    float* Ai        = Z + NN;
    float* Bi        = Ai + NN;
    float* Dj        = Bi + NN;
    float* Uj        = Dj + NN;
    float* Wj        = Uj + NN;
    float* blkmax    = Wj + NN;                   // 512
    int*   rank      = (int*)(blkmax + 512);      // N ints
    float* sortedD   = (float*)(rank + NN);       // N
    float* sortedRow = sortedD + NN;              // N*RS
    float* PP        = sortedRow + (size_t)NN*RS; // (N+1)*RS
    float* chunkSum  = PP + (size_t)(NN+1)*RS;    // NCH*RS

    lstm_fused_kernel<<<dim3(NN / 16), dim3(512), 0, stream>>>(
        x, Wih0, Whh0, bih0, bhh0, Wih1, Whh1, bih1, bhh1, last);
    gat_prep_kernel<<<dim3(NN / 16), dim3(256), 0, stream>>>(
        last, Wt, bt, a, s1, s2, blkmax);
    gat_finalize_kernel<<<dim3(32), dim3(256), 0, stream>>>(
        s1, s2, blkmax, Z, Ai, Bi, Dj, Uj, Wj, rank);
    rank_kernel<<<dim3(NN / 256, 8), dim3(256), 0, stream>>>(Dj, rank);
    scatter_kernel<<<dim3(NN / 32), dim3(256), 0, stream>>>(
        last, Dj, Uj, Wj, rank, sortedRow, sortedD);
    scanA_kernel<<<dim3(NCH), dim3(256), 0, stream>>>(sortedRow, chunkSum);
    scanC_kernel<<<dim3(NCH), dim3(256), 0, stream>>>(sortedRow, chunkSum, PP);
    applyfc_kernel<<<dim3(NN / 32), dim3(256), 0, stream>>>(
        last, Z, Ai, Bi, sortedD, PP, Wfc, bfc, Wout, bout, out);
}